// Round 12
// baseline (4086.317 us; speedup 1.0000x reference)
//
#include <hip/hip_runtime.h>

#define BN_EPS 1e-5f
#define GRID 1024
#define BSH 7          // bucket = dst >> 7 (128 nodes/bucket)
#define BMK 127

typedef _Float16 f16;
typedef _Float16 f16x8 __attribute__((ext_vector_type(8)));
typedef _Float16 f16x4 __attribute__((ext_vector_type(4)));
typedef float f32x4 __attribute__((ext_vector_type(4)));

struct KArgs {
    const float4* x; f16x4* xh; int n4;
    const int *src, *dst, *batch;
    const float *W1a,*b1a,*W1b,*b1b,*g1,*be1;
    const float *W2a,*b2a,*W2b,*b2b,*g2,*be2;
    const float *W3a,*b3a,*W3b,*b3b,*g3,*be3;
    const float *Wf1,*bf1,*Wf2,*bf2,*Wf3,*bf3;
    int N, E, G, NBK, CHUNK;
    int *bar, *hist, *btot, *boff, *off, *elist, *bucketed;
    f16 *Wh1a,*Wh1b,*Wh2a,*Wh2b,*Wh3a,*Wh3b;
    f16 *A1,*H1,*Y1,*Z1,*H2,*Y2,*Z2,*H3; float* Y3;
    float *st1,*st2,*st3,*v2,*v3,*pool,*out;
    float invN;
};

// ---- software grid barrier (cooperative-groups pattern; agent-scope fences
// do the L2 wb/inv needed for cross-XCD visibility). Grid co-residency is
// guaranteed: 1024 blocks, launch_bounds(256,4) => 4 blocks/CU * 256 CUs. ----
__device__ __forceinline__ void gsync(int* bar, int& ph) {
    __syncthreads();
    if (threadIdx.x == 0) {
        ph++;
        __threadfence();
        __hip_atomic_fetch_add(bar, 1, __ATOMIC_RELEASE, __HIP_MEMORY_SCOPE_AGENT);
        const int target = ph * GRID;
        while (__hip_atomic_load(bar, __ATOMIC_ACQUIRE, __HIP_MEMORY_SCOPE_AGENT) < target)
            __builtin_amdgcn_s_sleep(8);
        __threadfence();
    }
    __syncthreads();
}

// ---- wfrag mapping: W [FIN,FOUT] f32 -> MFMA-frag-ordered f16 ----
__device__ __forceinline__ void wfrag_one(const float* __restrict__ W, f16* __restrict__ out,
        int FIN, int FOUT, int f,
        const float* __restrict__ stats, const float* __restrict__ g, float invN) {
    int j = f & 7;
    int lane = (f >> 3) & 63;
    int tile = f >> 9;
    int NT = FOUT >> 4;
    int t = tile % NT, s = tile / NT;
    int k = s * 32 + (lane >> 4) * 8 + j;
    int n = t * 16 + (lane & 15);
    float w = W[(size_t)k * FOUT + n];
    if (stats) {
        float mu = stats[k] * invN;
        float var = fmaxf(stats[FIN + k] * invN - mu * mu, 0.0f);
        w *= rsqrtf(var + BN_EPS) * g[k];
    }
    out[f] = (f16)w;
}

// ---- gather phase (grid-stride virtual blocks) ----
template<int F, bool AFFINE>
__device__ void gather_phase(const int* __restrict__ off, const int* __restrict__ elist,
        const f16* __restrict__ in, f16* __restrict__ out,
        const float* __restrict__ v, const float* __restrict__ bias, int N) {
    constexpr int TPN = F / 8;
    constexpr int NPB = 256 / TPN;
    const int NV = (N + NPB - 1) / NPB;
    const int l = threadIdx.x & (TPN - 1);
    const int sl = threadIdx.x / TPN;
    const int j0 = l * 8;
    const f16x8* __restrict__ inv = (const f16x8*)in;
    for (int vb = blockIdx.x; vb < NV; vb += GRID) {
        const int i = vb * NPB + sl;
        if (i >= N) continue;
        f16x8 s = inv[(size_t)i * TPN + l];
        float a[8];
#pragma unroll
        for (int u = 0; u < 8; u++) a[u] = (float)s[u];
        int k = off[i], e = off[i + 1];
        const float cnt = (float)(e - k + 1);
        f16x8 c0, c1, c2, c3;
        if (k + 4 <= e) {
            c0 = inv[(size_t)elist[k + 0] * TPN + l];
            c1 = inv[(size_t)elist[k + 1] * TPN + l];
            c2 = inv[(size_t)elist[k + 2] * TPN + l];
            c3 = inv[(size_t)elist[k + 3] * TPN + l];
            k += 4;
            for (; k + 4 <= e; k += 4) {
                f16x8 d0 = inv[(size_t)elist[k + 0] * TPN + l];
                f16x8 d1 = inv[(size_t)elist[k + 1] * TPN + l];
                f16x8 d2 = inv[(size_t)elist[k + 2] * TPN + l];
                f16x8 d3 = inv[(size_t)elist[k + 3] * TPN + l];
#pragma unroll
                for (int u = 0; u < 8; u++)
                    a[u] += ((float)c0[u] + (float)c1[u]) + ((float)c2[u] + (float)c3[u]);
                c0 = d0; c1 = d1; c2 = d2; c3 = d3;
            }
#pragma unroll
            for (int u = 0; u < 8; u++)
                a[u] += ((float)c0[u] + (float)c1[u]) + ((float)c2[u] + (float)c3[u]);
        }
        for (; k < e; k++) {
            f16x8 p = inv[(size_t)elist[k] * TPN + l];
#pragma unroll
            for (int u = 0; u < 8; u++) a[u] += (float)p[u];
        }
        if (AFFINE) {
            float4 vv0 = *(const float4*)(v + j0);
            float4 vv1 = *(const float4*)(v + j0 + 4);
            float4 bb0 = *(const float4*)(bias + j0);
            float4 bb1 = *(const float4*)(bias + j0 + 4);
            a[0] = fmaxf(fmaf(cnt, vv0.x, a[0] + bb0.x), 0.0f);
            a[1] = fmaxf(fmaf(cnt, vv0.y, a[1] + bb0.y), 0.0f);
            a[2] = fmaxf(fmaf(cnt, vv0.z, a[2] + bb0.z), 0.0f);
            a[3] = fmaxf(fmaf(cnt, vv0.w, a[3] + bb0.w), 0.0f);
            a[4] = fmaxf(fmaf(cnt, vv1.x, a[4] + bb1.x), 0.0f);
            a[5] = fmaxf(fmaf(cnt, vv1.y, a[5] + bb1.y), 0.0f);
            a[6] = fmaxf(fmaf(cnt, vv1.z, a[6] + bb1.z), 0.0f);
            a[7] = fmaxf(fmaf(cnt, vv1.w, a[7] + bb1.w), 0.0f);
        }
        f16x8 o;
#pragma unroll
        for (int u = 0; u < 8; u++) o[u] = (f16)a[u];
        ((f16x8*)(out))[(size_t)i * TPN + l] = o;
    }
}

// ---- MFMA GEMM phase (pre-fragged W, column-tiled) ----
template<int FIN, int FOUT, int CT, bool STATS, bool RELU, bool BIAS, typename OutT>
__device__ void gemm_phase(const f16* __restrict__ A, const f16* __restrict__ Wf,
        const float* __restrict__ bias, OutT* __restrict__ Out,
        float* __restrict__ stats, int N, float* Ss) {
    constexpr int NS = FIN / 32;
    constexpr int NTF = FOUT / 16;
    constexpr int NT = CT / 16;
    constexpr int NCB = FOUT / CT;
    if (STATS) {
        for (int i = threadIdx.x; i < 2 * CT; i += 256) Ss[i] = 0.0f;
        __syncthreads();
    }
    const int cb = blockIdx.x % NCB;
    const int rb = blockIdx.x / NCB;
    const int RB = GRID / NCB;
    const int t0 = cb * NT;
    const int wid = threadIdx.x >> 6;
    const int lane = threadIdx.x & 63;
    const int col = lane & 15;
    const int quad = lane >> 4;

    f16x8 Bf[NS][NT];
#pragma unroll
    for (int s = 0; s < NS; s++)
#pragma unroll
        for (int t = 0; t < NT; t++)
            Bf[s][t] = *(const f16x8*)&Wf[((s * NTF + t0 + t) << 9) + (lane << 3)];

    float bj[NT];
#pragma unroll
    for (int t = 0; t < NT; t++) bj[t] = BIAS ? bias[(t0 + t) * 16 + col] : 0.0f;

    float ls[NT], ls2[NT];
#pragma unroll
    for (int t = 0; t < NT; t++) { ls[t] = 0.0f; ls2[t] = 0.0f; }

    const int S = N >> 4;
    for (int sidx = rb * 4 + wid; sidx < S; sidx += RB * 4) {
        const int m0 = sidx << 4;
        const f16* a0 = A + (size_t)(m0 + col) * FIN + (quad << 3);
        f16x8 Af[NS];
#pragma unroll
        for (int s = 0; s < NS; s++) Af[s] = *(const f16x8*)(a0 + s * 32);
        f32x4 acc[NT];
#pragma unroll
        for (int t = 0; t < NT; t++) acc[t] = (f32x4){bj[t], bj[t], bj[t], bj[t]};
#pragma unroll
        for (int t = 0; t < NT; t++)
#pragma unroll
            for (int s = 0; s < NS; s++)
                acc[t] = __builtin_amdgcn_mfma_f32_16x16x32_f16(Af[s], Bf[s][t], acc[t], 0, 0, 0);
#pragma unroll
        for (int t = 0; t < NT; t++) {
            float v0 = acc[t][0], v1 = acc[t][1], v2 = acc[t][2], v3 = acc[t][3];
            if (RELU) {
                v0 = fmaxf(v0, 0.0f); v1 = fmaxf(v1, 0.0f);
                v2 = fmaxf(v2, 0.0f); v3 = fmaxf(v3, 0.0f);
            }
            if (STATS) {
                ls[t]  += (v0 + v1) + (v2 + v3);
                ls2[t] += (v0 * v0 + v1 * v1) + (v2 * v2 + v3 * v3);
            }
            OutT* o = Out + (size_t)(m0 + quad * 4) * FOUT + (t0 + t) * 16 + col;
            o[0]        = (OutT)v0;
            o[FOUT]     = (OutT)v1;
            o[2 * FOUT] = (OutT)v2;
            o[3 * FOUT] = (OutT)v3;
        }
    }

    if (STATS) {
#pragma unroll
        for (int t = 0; t < NT; t++) {
            float s1 = ls[t], s2 = ls2[t];
            s1 += __shfl_xor(s1, 16); s1 += __shfl_xor(s1, 32);
            s2 += __shfl_xor(s2, 16); s2 += __shfl_xor(s2, 32);
            if (quad == 0) {
                atomicAdd(&Ss[t * 16 + col], s1);
                atomicAdd(&Ss[CT + t * 16 + col], s2);
            }
        }
        __syncthreads();
        for (int i = threadIdx.x; i < CT; i += 256) {
            atomicAdd(&stats[cb * CT + i], Ss[i]);
            atomicAdd(&stats[FOUT + cb * CT + i], Ss[CT + i]);
        }
        __syncthreads();
    }
}

// ---- BN3 + segmented pool ----
__device__ void bnpool_phase(const float* __restrict__ y, const float* __restrict__ st,
        const float* __restrict__ gw, const float* __restrict__ bw,
        const int* __restrict__ batch, float* __restrict__ pool, int N, float invN) {
    const int q = threadIdx.x >> 5, j = threadIdx.x & 31;
    const float mu = st[j] * invN;
    const float var = fmaxf(st[32 + j] * invN - mu * mu, 0.0f);
    const float sc = rsqrtf(var + BN_EPS) * gw[j];
    const float sh = bw[j] - mu * sc;
    const int NV = (N + 511) >> 9;
    for (int vb = blockIdx.x; vb < NV; vb += GRID) {
        int r0 = (vb * 8 + q) << 6;
        if (r0 >= N) continue;
        int r1 = min(r0 + 64, N);
        int curg = batch[r0];
        float acc = 0.0f;
        for (int r = r0; r < r1; r++) {
            int g = batch[r];
            if (g != curg) {
                atomicAdd(pool + (size_t)curg * 32 + j, acc);
                acc = 0.0f;
                curg = g;
            }
            acc = fmaf(y[(size_t)r * 32 + j], sc, sh + acc);
        }
        atomicAdd(pool + (size_t)curg * 32 + j, acc);
    }
}

// ---- FC head (2 graphs per 256-thr block) ----
__device__ void fc_phase(const float* __restrict__ pool,
        const float* __restrict__ Wf1, const float* __restrict__ bf1,
        const float* __restrict__ Wf2, const float* __restrict__ bf2,
        const float* __restrict__ Wf3, const float* __restrict__ bf3,
        float* __restrict__ out, int G, float* sm) {
    const int half = threadIdx.x >> 7;
    const int t = threadIdx.x & 127;
    float* zin = sm + half * 224;
    float* h1 = zin + 32;
    float* h2 = h1 + 128;
    const int NV = (G + 1) >> 1;
    for (int vb = blockIdx.x; vb < NV; vb += GRID) {
        const int g = vb * 2 + half;
        const bool act = g < G;
        __syncthreads();
        if (act && t < 32) zin[t] = pool[(size_t)g * 32 + t];
        __syncthreads();
        if (act) {
            float acc = bf1[t];
            for (int k = 0; k < 32; k++) acc = fmaf(zin[k], Wf1[k * 128 + t], acc);
            h1[t] = fmaxf(acc, 0.0f);
        }
        __syncthreads();
        if (act && t < 64) {
            float acc = bf2[t];
            for (int k = 0; k < 128; k++) acc = fmaf(h1[k], Wf2[k * 64 + t], acc);
            h2[t] = fmaxf(acc, 0.0f);
        }
        __syncthreads();
        if (act && t < 10) {
            float acc = bf3[t];
            for (int k = 0; k < 64; k++) acc = fmaf(h2[k], Wf3[k * 10 + t], acc);
            out[(size_t)g * 10 + t] = acc;
        }
    }
}

// ================= the one persistent kernel =================
__global__ __launch_bounds__(256, 4) void mega(KArgs a) {
    __shared__ int S[1024];   // 4 KB, reused by every phase
    int ph = 0;
    const int t = threadIdx.x;
    const int b = blockIdx.x;

    // ---- P0: x->f16 conv + static W frags + bucket count ----
    {
        const int BC = (a.n4 + 255) >> 8;
        const int NV = BC + 116 + GRID;
        for (int vb = b; vb < NV; vb += GRID) {
            int r = vb;
            if (r < BC) {
                int i = (r << 8) + t;
                if (i < a.n4) {
                    float4 vv = a.x[i];
                    f16x4 o;
                    o.x = (f16)vv.x; o.y = (f16)vv.y; o.z = (f16)vv.z; o.w = (f16)vv.w;
                    a.xh[i] = o;
                }
                continue;
            }
            r -= BC;
            if (r < 116) {
                if (r < 32)       wfrag_one(a.W1a, a.Wh1a, 64, 128, r * 256 + t, nullptr, nullptr, 0.f);
                else if (r < 96)  wfrag_one(a.W1b, a.Wh1b, 128, 128, (r - 32) * 256 + t, nullptr, nullptr, 0.f);
                else if (r < 112) wfrag_one(a.W2b, a.Wh2b, 64, 64, (r - 96) * 256 + t, nullptr, nullptr, 0.f);
                else              wfrag_one(a.W3b, a.Wh3b, 32, 32, (r - 112) * 256 + t, nullptr, nullptr, 0.f);
                continue;
            }
            r -= 116;   // bucket-count chunk id, exactly one per block
            for (int k = t; k < a.NBK; k += 256) S[k] = 0;
            __syncthreads();
            const int e0 = r * a.CHUNK, e1 = min(a.E, e0 + a.CHUNK);
            const int nq = (e1 - e0) >> 2;
            const int4* d4 = (const int4*)(a.dst + e0);
            for (int q = t; q < nq; q += 256) {
                int4 dv = d4[q];
                atomicAdd(&S[dv.x >> BSH], 1); atomicAdd(&S[dv.y >> BSH], 1);
                atomicAdd(&S[dv.z >> BSH], 1); atomicAdd(&S[dv.w >> BSH], 1);
            }
            for (int e = e0 + (nq << 2) + t; e < e1; e += 256) atomicAdd(&S[a.dst[e] >> BSH], 1);
            __syncthreads();
            for (int k = t; k < a.NBK; k += 256) a.hist[(size_t)k * GRID + r] = S[k];
            __syncthreads();
        }
    }

    gsync(a.bar, ph);
    // ---- P1: per-bucket exclusive scan over the 1024 chunk counts ----
    for (int vb = b; vb < a.NBK; vb += GRID) {
        int* h = a.hist + (size_t)vb * GRID;
        int x0 = h[t*4+0], x1 = h[t*4+1], x2 = h[t*4+2], x3 = h[t*4+3];
        int s0 = x0, s1 = s0 + x1, s2 = s1 + x2, s3 = s2 + x3;
        S[t] = s3;
        __syncthreads();
        for (int d = 1; d < 256; d <<= 1) {
            int u = (t >= d) ? S[t-d] : 0;
            __syncthreads();
            S[t] += u;
            __syncthreads();
        }
        int ex = S[t] - s3;
        h[t*4+0] = ex; h[t*4+1] = ex + s0; h[t*4+2] = ex + s1; h[t*4+3] = ex + s2;
        if (t == 255) a.btot[vb] = ex + s3;
        __syncthreads();
    }

    gsync(a.bar, ph);
    // ---- P2: bucket-offset scan (block 0) ----
    if (b == 0) {
        int x[4], s[4];
        int acc = 0;
        for (int k2 = 0; k2 < 4; k2++) {
            int idx = t * 4 + k2;
            x[k2] = (idx < a.NBK) ? a.btot[idx] : 0;
            acc += x[k2]; s[k2] = acc;
        }
        S[t] = acc;
        __syncthreads();
        for (int d = 1; d < 256; d <<= 1) {
            int u = (t >= d) ? S[t-d] : 0;
            __syncthreads();
            S[t] += u;
            __syncthreads();
        }
        int ex = S[t] - acc;
        for (int k2 = 0; k2 < 4; k2++) {
            int idx = t * 4 + k2;
            if (idx < a.NBK) a.boff[idx] = ex + s[k2] - x[k2];
        }
        if (t == 0) { a.boff[a.NBK] = a.E; a.off[a.N] = a.E; }
    }

    gsync(a.bar, ph);
    // ---- P3: scatter packed edges into bucket regions (LDS cursors) ----
    {
        for (int r = t; r < a.NBK; r += 256) S[r] = a.boff[r] + a.hist[(size_t)r * GRID + b];
        __syncthreads();
        const int e0 = b * a.CHUNK, e1 = min(a.E, e0 + a.CHUNK);
        const int nq = (e1 - e0) >> 2;
        const int4* d4 = (const int4*)(a.dst + e0);
        const int4* s4 = (const int4*)(a.src + e0);
        for (int q = t; q < nq; q += 256) {
            int4 dv = d4[q]; int4 sv = s4[q];
            int sl;
            sl = atomicAdd(&S[dv.x >> BSH], 1); a.bucketed[sl] = ((dv.x & BMK) << 18) | sv.x;
            sl = atomicAdd(&S[dv.y >> BSH], 1); a.bucketed[sl] = ((dv.y & BMK) << 18) | sv.y;
            sl = atomicAdd(&S[dv.z >> BSH], 1); a.bucketed[sl] = ((dv.z & BMK) << 18) | sv.z;
            sl = atomicAdd(&S[dv.w >> BSH], 1); a.bucketed[sl] = ((dv.w & BMK) << 18) | sv.w;
        }
        for (int e = e0 + (nq << 2) + t; e < e1; e += 256) {
            int d = a.dst[e];
            int sl = atomicAdd(&S[d >> BSH], 1);
            a.bucketed[sl] = ((d & BMK) << 18) | a.src[e];
        }
    }

    gsync(a.bar, ph);
    // ---- P4: per-bucket CSR finalize ----
    {
        int* lh = S; int* lc = S + 128; int* ts = S + 256;
        for (int vb = b; vb < a.NBK; vb += GRID) {
            const int b0 = vb << BSH;
            const int R = min(a.N - b0, 128);
            const int base = a.boff[vb], cnt = a.boff[vb + 1] - base;
            if (t < 128) lh[t] = 0;
            __syncthreads();
            for (int i = t; i < cnt; i += 256) atomicAdd(&lh[a.bucketed[base + i] >> 18], 1);
            __syncthreads();
            int v0 = 0;
            if (t < 128) { v0 = lh[t]; ts[t] = v0; }
            __syncthreads();
            for (int d = 1; d < 128; d <<= 1) {
                int u = 0;
                if (t < 128 && t >= d) u = ts[t-d];
                __syncthreads();
                if (t < 128) ts[t] += u;
                __syncthreads();
            }
            if (t < 128) { int ex = ts[t] - v0; lh[t] = ex; lc[t] = ex; }
            __syncthreads();
            if (t < R) a.off[b0 + t] = base + lh[t];
            for (int i = t; i < cnt; i += 256) {
                int p = a.bucketed[base + i];
                int rk = atomicAdd(&lc[p >> 18], 1);
                a.elist[base + rk] = p & 0x3FFFF;
            }
            __syncthreads();
        }
    }

    gsync(a.bar, ph);
    gather_phase<64, false>(a.off, a.elist, (const f16*)a.xh, a.A1, nullptr, nullptr, a.N);
    gsync(a.bar, ph);
    gemm_phase<64, 128, 64, false, true, true, f16>(a.A1, a.Wh1a, a.b1a, a.H1, nullptr, a.N, (float*)S);
    gsync(a.bar, ph);
    gemm_phase<128, 128, 64, true, true, true, f16>(a.H1, a.Wh1b, a.b1b, a.Y1, a.st1, a.N, (float*)S);
    gsync(a.bar, ph);
    // ---- prep2: v2 + BN-scaled wfrag of W2a ----
    for (int vb = b; vb < 33; vb += GRID) {
        if (vb == 0) {
            if (t < 64) {
                float acc = 0.0f;
                for (int k = 0; k < 128; k++) {
                    float mu = a.st1[k] * a.invN;
                    float var = fmaxf(a.st1[128 + k] * a.invN - mu * mu, 0.0f);
                    float sc = rsqrtf(var + BN_EPS) * a.g1[k];
                    float sh = a.be1[k] - mu * sc;
                    acc = fmaf(sh, a.W2a[(size_t)k * 64 + t], acc);
                }
                a.v2[t] = acc;
            }
        } else {
            wfrag_one(a.W2a, a.Wh2a, 128, 64, (vb - 1) * 256 + t, a.st1, a.g1, a.invN);
        }
    }
    gsync(a.bar, ph);
    gemm_phase<128, 64, 64, false, false, false, f16>(a.Y1, a.Wh2a, nullptr, a.Z1, nullptr, a.N, (float*)S);
    gsync(a.bar, ph);
    gather_phase<64, true>(a.off, a.elist, a.Z1, a.H2, a.v2, a.b2a, a.N);
    gsync(a.bar, ph);
    gemm_phase<64, 64, 64, true, true, true, f16>(a.H2, a.Wh2b, a.b2b, a.Y2, a.st2, a.N, (float*)S);
    gsync(a.bar, ph);
    // ---- prep3: v3 + BN-scaled wfrag of W3a ----
    for (int vb = b; vb < 9; vb += GRID) {
        if (vb == 0) {
            if (t < 32) {
                float acc = 0.0f;
                for (int k = 0; k < 64; k++) {
                    float mu = a.st2[k] * a.invN;
                    float var = fmaxf(a.st2[64 + k] * a.invN - mu * mu, 0.0f);
                    float sc = rsqrtf(var + BN_EPS) * a.g2[k];
                    float sh = a.be2[k] - mu * sc;
                    acc = fmaf(sh, a.W3a[(size_t)k * 32 + t], acc);
                }
                a.v3[t] = acc;
            }
        } else {
            wfrag_one(a.W3a, a.Wh3a, 64, 32, (vb - 1) * 256 + t, a.st2, a.g2, a.invN);
        }
    }
    gsync(a.bar, ph);
    gemm_phase<64, 32, 32, false, false, false, f16>(a.Y2, a.Wh3a, nullptr, a.Z2, nullptr, a.N, (float*)S);
    gsync(a.bar, ph);
    gather_phase<32, true>(a.off, a.elist, a.Z2, a.H3, a.v3, a.b3a, a.N);
    gsync(a.bar, ph);
    gemm_phase<32, 32, 32, true, true, true, float>(a.H3, a.Wh3b, a.b3b, a.Y3, a.st3, a.N, (float*)S);
    gsync(a.bar, ph);
    bnpool_phase(a.Y3, a.st3, a.g3, a.be3, a.batch, a.pool, a.N, a.invN);
    gsync(a.bar, ph);
    fc_phase(a.pool, a.Wf1, a.bf1, a.Wf2, a.bf2, a.Wf3, a.bf3, a.out, a.G, (float*)S);
}

extern "C" void kernel_launch(void* const* d_in, const int* in_sizes, int n_in,
                              void* d_out, int out_size, void* d_ws, size_t ws_size,
                              hipStream_t stream) {
    const float* x   = (const float*)d_in[0];
    const int*  ei   = (const int*)d_in[1];

    const int N = in_sizes[2];
    const int E = in_sizes[1] / 2;
    const int G = out_size / 10;
    const int NBK = (N + BMK) >> BSH;
    const int CHUNK = (((E + GRID - 1) / GRID) + 3) & ~3;

    // ---- ws layout ----
    float* B0   = (float*)d_ws;               // N*128 f32 worth
    float* B1   = B0 + (size_t)N * 128;       // N*128 f32 worth
    float* pool = B1 + (size_t)N * 128;       // G*32
    float* st1  = pool + (size_t)G * 32;      // 256
    float* st2  = st1 + 256;                  // 256
    float* st3  = st2 + 256;                  // 256
    int*   bar  = (int*)(st3 + 256);          // 16
    int*   off  = bar + 16;                   // N+1
    int*   elist= off + (N + 1);              // E
    float* v2   = (float*)(elist + E);        // 64
    float* v3   = v2 + 64;                    // 32
    int*   boff = (int*)(v3 + 32);            // NBK+1
    int*   btot = boff + (NBK + 1);           // NBK
    f16* Wh1a   = (f16*)(btot + NBK);
    f16* Wh1b   = Wh1a + 64 * 128;
    f16* Wh2a   = Wh1b + 128 * 128;
    f16* Wh2b   = Wh2a + 128 * 64;
    f16* Wh3a   = Wh2b + 64 * 64;
    f16* Wh3b   = Wh3a + 64 * 32;

    KArgs a;
    a.x = (const float4*)x;
    a.xh = (f16x4*)B0;                         // B0 slot A
    a.n4 = N * 16;
    a.src = ei; a.dst = ei + E; a.batch = (const int*)d_in[2];
    a.W1a = (const float*)d_in[3];  a.b1a = (const float*)d_in[4];
    a.W1b = (const float*)d_in[5];  a.b1b = (const float*)d_in[6];
    a.g1  = (const float*)d_in[7];  a.be1 = (const float*)d_in[8];
    a.W2a = (const float*)d_in[9];  a.b2a = (const float*)d_in[10];
    a.W2b = (const float*)d_in[11]; a.b2b = (const float*)d_in[12];
    a.g2  = (const float*)d_in[13]; a.be2 = (const float*)d_in[14];
    a.W3a = (const float*)d_in[15]; a.b3a = (const float*)d_in[16];
    a.W3b = (const float*)d_in[17]; a.b3b = (const float*)d_in[18];
    a.g3  = (const float*)d_in[19]; a.be3 = (const float*)d_in[20];
    a.Wf1 = (const float*)d_in[21]; a.bf1 = (const float*)d_in[22];
    a.Wf2 = (const float*)d_in[23]; a.bf2 = (const float*)d_in[24];
    a.Wf3 = (const float*)d_in[25]; a.bf3 = (const float*)d_in[26];
    a.N = N; a.E = E; a.G = G; a.NBK = NBK; a.CHUNK = CHUNK;
    a.bar = bar;
    a.bucketed = (int*)B1;                     // CSR phase (dead before A1)
    a.hist = a.bucketed + E;                   // NBK*GRID ints
    a.btot = btot; a.boff = boff; a.off = off; a.elist = elist;
    a.Wh1a = Wh1a; a.Wh1b = Wh1b; a.Wh2a = Wh2a; a.Wh2b = Wh2b; a.Wh3a = Wh3a; a.Wh3b = Wh3b;
    a.A1 = (f16*)B1;                           // B1 slot A (bucketed dead)
    a.H1 = (f16*)B0 + (size_t)N * 64;          // B0 slot B
    a.Y1 = (f16*)B1 + (size_t)N * 64;          // B1 slot B (hist dead)
    a.Z1 = (f16*)B0;                           // B0 slot A (xh dead)
    a.H2 = (f16*)B1;                           // B1 slot A (A1 dead)
    a.Y2 = (f16*)B0 + (size_t)N * 64;          // B0 slot B (H1 dead)
    a.Z2 = (f16*)B0;                           // B0 slot A (Z1 dead)
    a.H3 = (f16*)B1;                           // B1 slot A (H2 dead)
    a.Y3 = B1 + (size_t)N * 64;                // B1 slot B f32 (Y1 dead)
    a.st1 = st1; a.st2 = st2; a.st3 = st3; a.v2 = v2; a.v3 = v3; a.pool = pool;
    a.out = (float*)d_out;
    a.invN = 1.0f / (float)N;

    // zero pool + stats + barrier counter (contiguous)
    hipMemsetAsync(pool, 0, ((size_t)G * 32 + 768 + 16) * sizeof(float), stream);
    mega<<<GRID, 256, 0, stream>>>(a);
}

// Round 13
// 515.587 us; speedup vs baseline: 7.9256x; 7.9256x over previous
//
#include <hip/hip_runtime.h>

#define BN_EPS 1e-5f

typedef _Float16 f16;
typedef _Float16 f16x8 __attribute__((ext_vector_type(8)));
typedef _Float16 f16x4 __attribute__((ext_vector_type(4)));
typedef float f32x4 __attribute__((ext_vector_type(4)));

#define NBLK 512      // chunks in bucket count/scatter passes
#define BSHIFT 8      // bucket = dst >> 8  (256 nodes/bucket)
#define BMASK 255

// ======= wfrag mapping: W [FIN,FOUT] f32 -> MFMA-frag-ordered f16 =============
__device__ __forceinline__ void wfrag_one(const float* __restrict__ W, f16* __restrict__ out,
        int FIN, int FOUT, int f,
        const float* __restrict__ stats, const float* __restrict__ g, float invN) {
    int j = f & 7;
    int lane = (f >> 3) & 63;
    int tile = f >> 9;
    int NT = FOUT >> 4;
    int t = tile % NT, s = tile / NT;
    int k = s * 32 + (lane >> 4) * 8 + j;
    int n = t * 16 + (lane & 15);
    float w = W[(size_t)k * FOUT + n];
    if (stats) {
        float mu = stats[k] * invN;
        float var = fmaxf(stats[FIN + k] * invN - mu * mu, 0.0f);
        w *= rsqrtf(var + BN_EPS) * g[k];
    }
    out[f] = (f16)w;
}

// ========== fused setup: x->f16 conv + static W frags + bucket count ==========
__global__ __launch_bounds__(256) void setup_count(const float4* __restrict__ x,
        f16x4* __restrict__ xh, int n4,
        const float* __restrict__ W1a, f16* __restrict__ Wh1a,
        const float* __restrict__ W1b, f16* __restrict__ Wh1b,
        const float* __restrict__ W2b, f16* __restrict__ Wh2b,
        const float* __restrict__ W3b, f16* __restrict__ Wh3b,
        const int* __restrict__ dst, int* __restrict__ hist,
        int NBK, int CHUNK, int E) {
    __shared__ int lh[512];
    const int BC = (n4 + 255) / 256;
    int bid = blockIdx.x;
    const int t = threadIdx.x;
    if (bid < BC) {
        int i = bid * 256 + t;
        if (i < n4) {
            float4 v = x[i];
            f16x4 o;
            o.x = (f16)v.x; o.y = (f16)v.y; o.z = (f16)v.z; o.w = (f16)v.w;
            xh[i] = o;
        }
        return;
    }
    bid -= BC;
    if (bid < 116) {
        if (bid < 32)       wfrag_one(W1a, Wh1a, 64, 128, bid * 256 + t, nullptr, nullptr, 0.f);
        else if (bid < 96)  wfrag_one(W1b, Wh1b, 128, 128, (bid - 32) * 256 + t, nullptr, nullptr, 0.f);
        else if (bid < 112) wfrag_one(W2b, Wh2b, 64, 64, (bid - 96) * 256 + t, nullptr, nullptr, 0.f);
        else                wfrag_one(W3b, Wh3b, 32, 32, (bid - 112) * 256 + t, nullptr, nullptr, 0.f);
        return;
    }
    const int blk = bid - 116;   // chunk id, one per block
    for (int r = t; r < 512; r += 256) lh[r] = 0;
    __syncthreads();
    const int e0 = blk * CHUNK, e1 = min(E, e0 + CHUNK);
    const int nq = (e1 - e0) >> 2;
    const int4* d4 = (const int4*)(dst + e0);
    for (int q = t; q < nq; q += 256) {
        int4 v = d4[q];
        atomicAdd(&lh[v.x >> BSHIFT], 1);
        atomicAdd(&lh[v.y >> BSHIFT], 1);
        atomicAdd(&lh[v.z >> BSHIFT], 1);
        atomicAdd(&lh[v.w >> BSHIFT], 1);
    }
    for (int e = e0 + (nq << 2) + t; e < e1; e += 256) atomicAdd(&lh[dst[e] >> BSHIFT], 1);
    __syncthreads();
    for (int r = t; r < NBK; r += 256) hist[r * NBLK + blk] = lh[r];
}

// per-bucket exclusive scan over chunk counts; emit bucket totals
__global__ __launch_bounds__(512) void bkt_bscan(int* __restrict__ hist,
        int* __restrict__ btot) {
    __shared__ int sh[512];
    const int b = blockIdx.x, t = threadIdx.x;
    int v = hist[b * NBLK + t];
    sh[t] = v;
    __syncthreads();
    for (int d = 1; d < 512; d <<= 1) {
        int u = (t >= d) ? sh[t - d] : 0;
        __syncthreads();
        sh[t] += u;
        __syncthreads();
    }
    hist[b * NBLK + t] = sh[t] - v;        // exclusive
    if (t == 511) btot[b] = sh[511];
}

// scatter packed (local_dst<<18 | src); computes bucket bases from btot in LDS
__global__ __launch_bounds__(512) void bkt_scatter(const int* __restrict__ src,
        const int* __restrict__ dst, const int* __restrict__ hist,
        const int* __restrict__ btot, int* __restrict__ bucketed,
        int NBK, int CHUNK, int E) {
    __shared__ int sc[512];
    __shared__ int lc[512];
    const int blk = blockIdx.x, t = threadIdx.x;
    int v = (t < NBK) ? btot[t] : 0;
    sc[t] = v;
    __syncthreads();
    for (int d = 1; d < 512; d <<= 1) {
        int u = (t >= d) ? sc[t - d] : 0;
        __syncthreads();
        sc[t] += u;
        __syncthreads();
    }
    if (t < NBK) lc[t] = (sc[t] - v) + hist[t * NBLK + blk];   // boff_ex + chunk off
    __syncthreads();
    const int e0 = blk * CHUNK, e1 = min(E, e0 + CHUNK);
    const int nq = (e1 - e0) >> 2;
    const int4* d4 = (const int4*)(dst + e0);
    const int4* s4 = (const int4*)(src + e0);
    for (int q = t; q < nq; q += 512) {
        int4 d = d4[q];
        int4 s = s4[q];
        int sl;
        sl = atomicAdd(&lc[d.x >> BSHIFT], 1); bucketed[sl] = ((d.x & BMASK) << 18) | s.x;
        sl = atomicAdd(&lc[d.y >> BSHIFT], 1); bucketed[sl] = ((d.y & BMASK) << 18) | s.y;
        sl = atomicAdd(&lc[d.z >> BSHIFT], 1); bucketed[sl] = ((d.z & BMASK) << 18) | s.z;
        sl = atomicAdd(&lc[d.w >> BSHIFT], 1); bucketed[sl] = ((d.w & BMASK) << 18) | s.w;
    }
    for (int e = e0 + (nq << 2) + t; e < e1; e += 512) {
        int d = dst[e];
        int slot = atomicAdd(&lc[d >> BSHIFT], 1);
        bucketed[slot] = ((d & BMASK) << 18) | src[e];
    }
}

// per-bucket CSR finalize; computes own boff from btot in LDS
__global__ __launch_bounds__(512) void bkt_csr(const int* __restrict__ bucketed,
        const int* __restrict__ btot, int* __restrict__ off,
        int* __restrict__ elist, int NBK, int N, int E) {
    __shared__ int sc[512];
    __shared__ int lh[256];
    __shared__ int lc[256];
    __shared__ int sh[256];
    const int b = blockIdx.x, t = threadIdx.x;
    int v = (t < NBK) ? btot[t] : 0;
    sc[t] = v;
    __syncthreads();
    for (int d = 1; d < 512; d <<= 1) {
        int u = (t >= d) ? sc[t - d] : 0;
        __syncthreads();
        sc[t] += u;
        __syncthreads();
    }
    const int cnt  = btot[b];
    const int base = sc[b] - cnt;        // exclusive boff[b]
    if (b == 0 && t == 0) off[N] = E;
    const int b0 = b << BSHIFT;
    const int R = min(N - b0, 256);
    if (t < 256) lh[t] = 0;
    __syncthreads();
    for (int i = t; i < cnt; i += 512) atomicAdd(&lh[bucketed[base + i] >> 18], 1);
    __syncthreads();
    int v0 = 0;
    if (t < 256) { v0 = lh[t]; sh[t] = v0; }
    __syncthreads();
    for (int d = 1; d < 256; d <<= 1) {
        int u = 0;
        if (t < 256 && t >= d) u = sh[t - d];
        __syncthreads();
        if (t < 256) sh[t] += u;
        __syncthreads();
    }
    if (t < 256) { int ex = sh[t] - v0; lh[t] = ex; lc[t] = ex; }
    __syncthreads();
    if (t < R) off[b0 + t] = base + lh[t];
    for (int i = t; i < cnt; i += 512) {
        int p = bucketed[base + i];
        int rk = atomicAdd(&lc[p >> 18], 1);
        elist[base + rk] = p & 0x3FFFF;
    }
}

// ======== gather: f16x8 lanes, group-4 software pipeline (prefetch) ===========
template<int F, bool AFFINE>
__global__ __launch_bounds__(256) void gather_v(const int* __restrict__ off,
        const int* __restrict__ elist, const f16* __restrict__ in,
        f16* __restrict__ out, const float* __restrict__ v,
        const float* __restrict__ bias, int N) {
    constexpr int TPN = F / 8;
    constexpr int NPB = 256 / TPN;
    const int i = blockIdx.x * NPB + threadIdx.x / TPN;
    const int l = threadIdx.x & (TPN - 1);
    if (i >= N) return;
    const int j0 = l * 8;
    const f16x8* __restrict__ inv = (const f16x8*)in;
    f16x8 s = inv[(size_t)i * TPN + l];
    float a[8];
#pragma unroll
    for (int u = 0; u < 8; u++) a[u] = (float)s[u];
    int k = off[i], e = off[i + 1];
    const float cnt = (float)(e - k + 1);
    f16x8 c0, c1, c2, c3;
    if (k + 4 <= e) {
        c0 = inv[(size_t)elist[k + 0] * TPN + l];
        c1 = inv[(size_t)elist[k + 1] * TPN + l];
        c2 = inv[(size_t)elist[k + 2] * TPN + l];
        c3 = inv[(size_t)elist[k + 3] * TPN + l];
        k += 4;
        for (; k + 4 <= e; k += 4) {
            f16x8 d0 = inv[(size_t)elist[k + 0] * TPN + l];
            f16x8 d1 = inv[(size_t)elist[k + 1] * TPN + l];
            f16x8 d2 = inv[(size_t)elist[k + 2] * TPN + l];
            f16x8 d3 = inv[(size_t)elist[k + 3] * TPN + l];
#pragma unroll
            for (int u = 0; u < 8; u++)
                a[u] += ((float)c0[u] + (float)c1[u]) + ((float)c2[u] + (float)c3[u]);
            c0 = d0; c1 = d1; c2 = d2; c3 = d3;
        }
#pragma unroll
        for (int u = 0; u < 8; u++)
            a[u] += ((float)c0[u] + (float)c1[u]) + ((float)c2[u] + (float)c3[u]);
    }
    for (; k < e; k++) {
        f16x8 p = inv[(size_t)elist[k] * TPN + l];
#pragma unroll
        for (int u = 0; u < 8; u++) a[u] += (float)p[u];
    }
    if (AFFINE) {
        float4 vv0 = *(const float4*)(v + j0);
        float4 vv1 = *(const float4*)(v + j0 + 4);
        float4 bb0 = *(const float4*)(bias + j0);
        float4 bb1 = *(const float4*)(bias + j0 + 4);
        a[0] = fmaxf(fmaf(cnt, vv0.x, a[0] + bb0.x), 0.0f);
        a[1] = fmaxf(fmaf(cnt, vv0.y, a[1] + bb0.y), 0.0f);
        a[2] = fmaxf(fmaf(cnt, vv0.z, a[2] + bb0.z), 0.0f);
        a[3] = fmaxf(fmaf(cnt, vv0.w, a[3] + bb0.w), 0.0f);
        a[4] = fmaxf(fmaf(cnt, vv1.x, a[4] + bb1.x), 0.0f);
        a[5] = fmaxf(fmaf(cnt, vv1.y, a[5] + bb1.y), 0.0f);
        a[6] = fmaxf(fmaf(cnt, vv1.z, a[6] + bb1.z), 0.0f);
        a[7] = fmaxf(fmaf(cnt, vv1.w, a[7] + bb1.w), 0.0f);
    }
    f16x8 o;
#pragma unroll
    for (int u = 0; u < 8; u++) o[u] = (f16)a[u];
    ((f16x8*)(out))[(size_t)i * TPN + l] = o;
}

// ===== fused layer prep: block 0 computes v[]; blocks 1.. do scaled wfrag =====
__global__ __launch_bounds__(256) void layerprep_kernel(const float* __restrict__ W,
        f16* __restrict__ Wh, int FIN, int FOUT,
        const float* __restrict__ stats, const float* __restrict__ g,
        const float* __restrict__ be, float* __restrict__ v, float invN) {
    if (blockIdx.x == 0) {
        int j = threadIdx.x;
        if (j >= FOUT) return;
        float acc = 0.0f;
        for (int k = 0; k < FIN; k++) {
            float mu = stats[k] * invN;
            float var = fmaxf(stats[FIN + k] * invN - mu * mu, 0.0f);
            float sc = rsqrtf(var + BN_EPS) * g[k];
            float sh = be[k] - mu * sc;
            acc = fmaf(sh, W[(size_t)k * FOUT + j], acc);
        }
        v[j] = acc;
        return;
    }
    int f = (blockIdx.x - 1) * 256 + threadIdx.x;
    if (f < FIN * FOUT) wfrag_one(W, Wh, FIN, FOUT, f, stats, g, invN);
}

// ======= MFMA GEMM (pre-fragged W, column-tiled to cap VGPR pressure) =========
template<int FIN, int FOUT, int CT, bool STATS, bool RELU, bool BIAS, typename OutT>
__global__ __launch_bounds__(256) void gemm_mfma(const f16* __restrict__ A,
        const f16* __restrict__ Wf, const float* __restrict__ bias,
        OutT* __restrict__ Out, float* __restrict__ stats, int N) {
    constexpr int NS = FIN / 32;
    constexpr int NTF = FOUT / 16;
    constexpr int NT = CT / 16;
    constexpr int NCB = FOUT / CT;
    __shared__ float Ss[STATS ? 2 * CT : 1];
    if (STATS) {
        for (int i = threadIdx.x; i < 2 * CT; i += 256) Ss[i] = 0.0f;
        __syncthreads();
    }
    const int cb = blockIdx.x % NCB;
    const int rb = blockIdx.x / NCB;
    const int RB = gridDim.x / NCB;
    const int t0 = cb * NT;
    const int wid = threadIdx.x >> 6;
    const int lane = threadIdx.x & 63;
    const int col = lane & 15;
    const int quad = lane >> 4;

    f16x8 Bf[NS][NT];
#pragma unroll
    for (int s = 0; s < NS; s++)
#pragma unroll
        for (int t = 0; t < NT; t++)
            Bf[s][t] = *(const f16x8*)&Wf[((s * NTF + t0 + t) << 9) + (lane << 3)];

    float bj[NT];
#pragma unroll
    for (int t = 0; t < NT; t++) bj[t] = BIAS ? bias[(t0 + t) * 16 + col] : 0.0f;

    float ls[NT], ls2[NT];
#pragma unroll
    for (int t = 0; t < NT; t++) { ls[t] = 0.0f; ls2[t] = 0.0f; }

    const int S = N >> 4;
    for (int sidx = rb * 4 + wid; sidx < S; sidx += RB * 4) {
        const int m0 = sidx << 4;
        const f16* a0 = A + (size_t)(m0 + col) * FIN + (quad << 3);
        f16x8 Af[NS];
#pragma unroll
        for (int s = 0; s < NS; s++) Af[s] = *(const f16x8*)(a0 + s * 32);
        f32x4 acc[NT];
#pragma unroll
        for (int t = 0; t < NT; t++) acc[t] = (f32x4){bj[t], bj[t], bj[t], bj[t]};
#pragma unroll
        for (int t = 0; t < NT; t++)
#pragma unroll
            for (int s = 0; s < NS; s++)
                acc[t] = __builtin_amdgcn_mfma_f32_16x16x32_f16(Af[s], Bf[s][t], acc[t], 0, 0, 0);
#pragma unroll
        for (int t = 0; t < NT; t++) {
            float v0 = acc[t][0], v1 = acc[t][1], v2 = acc[t][2], v3 = acc[t][3];
            if (RELU) {
                v0 = fmaxf(v0, 0.0f); v1 = fmaxf(v1, 0.0f);
                v2 = fmaxf(v2, 0.0f); v3 = fmaxf(v3, 0.0f);
            }
            if (STATS) {
                ls[t]  += (v0 + v1) + (v2 + v3);
                ls2[t] += (v0 * v0 + v1 * v1) + (v2 * v2 + v3 * v3);
            }
            OutT* o = Out + (size_t)(m0 + quad * 4) * FOUT + (t0 + t) * 16 + col;
            o[0]        = (OutT)v0;
            o[FOUT]     = (OutT)v1;
            o[2 * FOUT] = (OutT)v2;
            o[3 * FOUT] = (OutT)v3;
        }
    }

    if (STATS) {
#pragma unroll
        for (int t = 0; t < NT; t++) {
            float s1 = ls[t], s2 = ls2[t];
            s1 += __shfl_xor(s1, 16); s1 += __shfl_xor(s1, 32);
            s2 += __shfl_xor(s2, 16); s2 += __shfl_xor(s2, 32);
            if (quad == 0) {
                atomicAdd(&Ss[t * 16 + col], s1);
                atomicAdd(&Ss[CT + t * 16 + col], s2);
            }
        }
        __syncthreads();
        for (int i = threadIdx.x; i < CT; i += 256) {
            atomicAdd(&stats[cb * CT + i], Ss[i]);
            atomicAdd(&stats[FOUT + cb * CT + i], Ss[CT + i]);
        }
    }
}

// ================= layer-3 BN + segmented pool (batch sorted) =================
__global__ __launch_bounds__(256) void bn_pool_kernel(const float* __restrict__ y,
        const float* __restrict__ stats, const float* __restrict__ gw,
        const float* __restrict__ bw, const int* __restrict__ batch,
        float* __restrict__ pool, int N, float invN) {
    constexpr int F = 32, CH = 64;
    int q = threadIdx.x >> 5;
    int j = threadIdx.x & 31;
    int r0 = (blockIdx.x * 8 + q) * CH;
    if (r0 >= N) return;
    int r1 = min(r0 + CH, N);
    float mu = stats[j] * invN;
    float var = fmaxf(stats[F + j] * invN - mu * mu, 0.0f);
    float sc = rsqrtf(var + BN_EPS) * gw[j];
    float sh = bw[j] - mu * sc;
    int curg = batch[r0];
    float acc = 0.0f;
    for (int r = r0; r < r1; r++) {
        int g = batch[r];
        if (g != curg) {
            atomicAdd(pool + (size_t)curg * 32 + j, acc);
            acc = 0.0f;
            curg = g;
        }
        acc = fmaf(y[(size_t)r * 32 + j], sc, sh + acc);
    }
    atomicAdd(pool + (size_t)curg * 32 + j, acc);
}

// ================= FC head =================
__global__ __launch_bounds__(128) void fc_kernel(const float* __restrict__ pool,
        const float* __restrict__ Wf1, const float* __restrict__ bf1,
        const float* __restrict__ Wf2, const float* __restrict__ bf2,
        const float* __restrict__ Wf3, const float* __restrict__ bf3,
        float* __restrict__ out) {
    __shared__ float zin[32];
    __shared__ float h1[128];
    __shared__ float h2[64];
    const int gidx = blockIdx.x;
    const int t = threadIdx.x;
    if (t < 32) zin[t] = pool[(size_t)gidx * 32 + t];
    __syncthreads();
    {
        float a = bf1[t];
        for (int k = 0; k < 32; k++) a = fmaf(zin[k], Wf1[k * 128 + t], a);
        h1[t] = fmaxf(a, 0.0f);
    }
    __syncthreads();
    if (t < 64) {
        float a = bf2[t];
        for (int k = 0; k < 128; k++) a = fmaf(h1[k], Wf2[k * 64 + t], a);
        h2[t] = fmaxf(a, 0.0f);
    }
    __syncthreads();
    if (t < 10) {
        float a = bf3[t];
        for (int k = 0; k < 64; k++) a = fmaf(h2[k], Wf3[k * 10 + t], a);
        out[(size_t)gidx * 10 + t] = a;
    }
}

extern "C" void kernel_launch(void* const* d_in, const int* in_sizes, int n_in,
                              void* d_out, int out_size, void* d_ws, size_t ws_size,
                              hipStream_t stream) {
    const float* x   = (const float*)d_in[0];
    const int*  ei   = (const int*)d_in[1];
    const int*  batch= (const int*)d_in[2];
    const float* W1a = (const float*)d_in[3];  const float* b1a = (const float*)d_in[4];
    const float* W1b = (const float*)d_in[5];  const float* b1b = (const float*)d_in[6];
    const float* g1  = (const float*)d_in[7];  const float* be1 = (const float*)d_in[8];
    const float* W2a = (const float*)d_in[9];  const float* b2a = (const float*)d_in[10];
    const float* W2b = (const float*)d_in[11]; const float* b2b = (const float*)d_in[12];
    const float* g2  = (const float*)d_in[13]; const float* be2 = (const float*)d_in[14];
    const float* W3a = (const float*)d_in[15]; const float* b3a = (const float*)d_in[16];
    const float* W3b = (const float*)d_in[17]; const float* b3b = (const float*)d_in[18];
    const float* g3  = (const float*)d_in[19]; const float* be3 = (const float*)d_in[20];
    const float* Wf1 = (const float*)d_in[21]; const float* bf1 = (const float*)d_in[22];
    const float* Wf2 = (const float*)d_in[23]; const float* bf2 = (const float*)d_in[24];
    const float* Wf3 = (const float*)d_in[25]; const float* bf3 = (const float*)d_in[26];

    const int N = in_sizes[2];
    const int E = in_sizes[1] / 2;
    const int G = out_size / 10;
    const int* src = ei;
    const int* dst = ei + E;

    const int NBK = (N + BMASK) >> BSHIFT;           // 391 for N=100K
    const int CHUNK = (((E + NBLK - 1) / NBLK) + 3) & ~3;  // 4-aligned

    // ---- dedicated ws regions ----
    float* B0   = (float*)d_ws;              // N*128 f32 worth (= N*256 f16)
    float* B1   = B0 + (size_t)N * 128;
    float* pool = B1 + (size_t)N * 128;      // G*32
    float* st1  = pool + (size_t)G * 32;     // 256 each
    float* st2  = st1 + 256;
    float* st3  = st2 + 256;
    int* off    = (int*)(st3 + 256);         // N+1
    int* elist  = off + (N + 1);             // E
    float* v2   = (float*)(elist + E);       // 64
    float* v3   = v2 + 64;                   // 32
    int* btot   = (int*)(v3 + 32);           // NBK
    f16* Wh1a   = (f16*)(btot + NBK);        // 8K
    f16* Wh1b   = Wh1a + 64 * 128;           // 16K
    f16* Wh2a   = Wh1b + 128 * 128;          // 8K
    f16* Wh2b   = Wh2a + 128 * 64;           // 4K
    f16* Wh3a   = Wh2b + 64 * 64;            // 2K
    f16* Wh3b   = Wh3a + 64 * 32;            // 1K

    // ---- CSR-phase aliases in B1 (dead before B1's activation use) ----
    int* bucketed = (int*)B1;                // E ints (12.8 MB)
    int* hist     = bucketed + E;            // NBK*NBLK ints (800 KB)

    // ---- activation aliases (stream-order safe) ----
    f16* xh    = (f16*)B0;                    // N*64  [B0 slot A]
    f16* A1    = (f16*)B1;                    // N*64  [B1 slot A] (bucketed dead)
    f16* H1    = (f16*)B0 + (size_t)N * 64;   // N*128 [B0 slot B]
    f16* Y1    = (f16*)B1 + (size_t)N * 64;   // N*128 [B1 slot B] (hist dead)
    f16* Z1    = (f16*)B0;                    // N*64  [B0 slot A] (xh dead)
    f16* H2    = (f16*)B1;                    // N*64  [B1 slot A] (A1 dead)
    f16* Y2    = (f16*)B0 + (size_t)N * 64;   // N*64  [B0 slot B] (H1 dead)
    f16* Z2    = (f16*)B0;                    // N*32  [B0 slot A] (Z1 dead)
    f16* H3    = (f16*)B1;                    // N*32  [B1 slot A] (H2 dead)
    float* Y3  = B1 + (size_t)N * 64;         // N*32 f32 [B1 slot B] (Y1 dead)

    hipMemsetAsync(pool, 0, ((size_t)G * 32 + 768) * sizeof(float), stream);

    const float invN = 1.0f / (float)N;
    const int GG = 640;

    // ---- fused setup: conv + static W frags + bucket count ----
    {
        int BC = (N * 16 + 255) / 256;
        setup_count<<<BC + 116 + NBLK, 256, 0, stream>>>(
            (const float4*)x, (f16x4*)xh, N * 16,
            W1a, Wh1a, W1b, Wh1b, W2b, Wh2b, W3b, Wh3b,
            dst, hist, NBK, CHUNK, E);
    }

    // ---- CSR build ----
    bkt_bscan  <<<NBK, 512, 0, stream>>>(hist, btot);
    bkt_scatter<<<NBLK, 512, 0, stream>>>(src, dst, hist, btot, bucketed, NBK, CHUNK, E);
    bkt_csr    <<<NBK, 512, 0, stream>>>(bucketed, btot, off, elist, NBK, N, E);

    // ---- Layer 1 ----
    gather_v<64, false><<<(N + 31) / 32, 256, 0, stream>>>(off, elist, xh, A1, nullptr, nullptr, N);
    gemm_mfma<64, 128, 64, false, true, true, f16><<<GG, 256, 0, stream>>>(A1, Wh1a, b1a, H1, nullptr, N);
    gemm_mfma<128, 128, 64, true, true, true, f16><<<GG, 256, 0, stream>>>(H1, Wh1b, b1b, Y1, st1, N);

    // ---- Layer 2 (commuted) ----
    layerprep_kernel<<<33, 256, 0, stream>>>(W2a, Wh2a, 128, 64, st1, g1, be1, v2, invN);
    gemm_mfma<128, 64, 64, false, false, false, f16><<<GG, 256, 0, stream>>>(Y1, Wh2a, nullptr, Z1, nullptr, N);
    gather_v<64, true><<<(N + 31) / 32, 256, 0, stream>>>(off, elist, Z1, H2, v2, b2a, N);
    gemm_mfma<64, 64, 64, true, true, true, f16><<<GG, 256, 0, stream>>>(H2, Wh2b, b2b, Y2, st2, N);

    // ---- Layer 3 (commuted) ----
    layerprep_kernel<<<9, 256, 0, stream>>>(W3a, Wh3a, 64, 32, st2, g2, be2, v3, invN);
    gemm_mfma<64, 32, 32, false, false, false, f16><<<GG, 256, 0, stream>>>(Y2, Wh3a, nullptr, Z2, nullptr, N);
    gather_v<32, true><<<(N + 63) / 64, 256, 0, stream>>>(off, elist, Z2, H3, v3, b3a, N);
    gemm_mfma<32, 32, 32, true, true, true, float><<<GG, 256, 0, stream>>>(H3, Wh3b, b3b, Y3, st3, N);

    // ---- BN3 + segmented pool ----
    bn_pool_kernel<<<(N + 511) / 512, 256, 0, stream>>>(Y3, st3, g3, be3, batch, pool, N, invN);

    // ---- pooled MLP head ----
    fc_kernel<<<G, 128, 0, stream>>>(pool, Wf1, bf1, Wf2, bf2, Wf3, bf3, (float*)d_out);
}

// Round 14
// 492.986 us; speedup vs baseline: 8.2889x; 1.0458x over previous
//
#include <hip/hip_runtime.h>

#define BN_EPS 1e-5f

typedef _Float16 f16;
typedef _Float16 f16x8 __attribute__((ext_vector_type(8)));
typedef _Float16 f16x4 __attribute__((ext_vector_type(4)));
typedef float f32x4 __attribute__((ext_vector_type(4)));

#define NBLK 512      // chunks in bucket count/scatter passes
#define BSHIFT 8      // bucket = dst >> 8  (256 nodes/bucket)
#define BMASK 255

// ======= wfrag mapping: W [FIN,FOUT] f32 -> MFMA-frag-ordered f16 =============
// stats may be NC strided copies (stride 2*FIN): sum then BN-scale.
__device__ __forceinline__ void wfrag_one(const float* __restrict__ W, f16* __restrict__ out,
        int FIN, int FOUT, int f,
        const float* __restrict__ stats, int NC, const float* __restrict__ g, float invN) {
    int j = f & 7;
    int lane = (f >> 3) & 63;
    int tile = f >> 9;
    int NT = FOUT >> 4;
    int t = tile % NT, s = tile / NT;
    int k = s * 32 + (lane >> 4) * 8 + j;
    int n = t * 16 + (lane & 15);
    float w = W[(size_t)k * FOUT + n];
    if (stats) {
        float s1 = 0.0f, s2 = 0.0f;
        for (int c = 0; c < NC; c++) {
            s1 += stats[c * 2 * FIN + k];
            s2 += stats[c * 2 * FIN + FIN + k];
        }
        float mu = s1 * invN;
        float var = fmaxf(s2 * invN - mu * mu, 0.0f);
        w *= rsqrtf(var + BN_EPS) * g[k];
    }
    out[f] = (f16)w;
}

// ========== fused setup: x->f16 conv + static W frags + bucket count ==========
__global__ __launch_bounds__(256) void setup_count(const float4* __restrict__ x,
        f16x4* __restrict__ xh, int n4,
        const float* __restrict__ W1a, f16* __restrict__ Wh1a,
        const float* __restrict__ W1b, f16* __restrict__ Wh1b,
        const float* __restrict__ W2b, f16* __restrict__ Wh2b,
        const float* __restrict__ W3b, f16* __restrict__ Wh3b,
        const int* __restrict__ dst, int* __restrict__ hist,
        int NBK, int CHUNK, int E) {
    __shared__ int lh[512];
    const int BC = (n4 + 255) / 256;
    int bid = blockIdx.x;
    const int t = threadIdx.x;
    if (bid < BC) {
        int i = bid * 256 + t;
        if (i < n4) {
            float4 v = x[i];
            f16x4 o;
            o.x = (f16)v.x; o.y = (f16)v.y; o.z = (f16)v.z; o.w = (f16)v.w;
            xh[i] = o;
        }
        return;
    }
    bid -= BC;
    if (bid < 116) {
        if (bid < 32)       wfrag_one(W1a, Wh1a, 64, 128, bid * 256 + t, nullptr, 1, nullptr, 0.f);
        else if (bid < 96)  wfrag_one(W1b, Wh1b, 128, 128, (bid - 32) * 256 + t, nullptr, 1, nullptr, 0.f);
        else if (bid < 112) wfrag_one(W2b, Wh2b, 64, 64, (bid - 96) * 256 + t, nullptr, 1, nullptr, 0.f);
        else                wfrag_one(W3b, Wh3b, 32, 32, (bid - 112) * 256 + t, nullptr, 1, nullptr, 0.f);
        return;
    }
    const int blk = bid - 116;   // chunk id, one per block
    for (int r = t; r < 512; r += 256) lh[r] = 0;
    __syncthreads();
    const int e0 = blk * CHUNK, e1 = min(E, e0 + CHUNK);
    const int nq = (e1 - e0) >> 2;
    const int4* d4 = (const int4*)(dst + e0);
    for (int q = t; q < nq; q += 256) {
        int4 v = d4[q];
        atomicAdd(&lh[v.x >> BSHIFT], 1);
        atomicAdd(&lh[v.y >> BSHIFT], 1);
        atomicAdd(&lh[v.z >> BSHIFT], 1);
        atomicAdd(&lh[v.w >> BSHIFT], 1);
    }
    for (int e = e0 + (nq << 2) + t; e < e1; e += 256) atomicAdd(&lh[dst[e] >> BSHIFT], 1);
    __syncthreads();
    for (int r = t; r < NBK; r += 256) hist[r * NBLK + blk] = lh[r];
}

// per-bucket exclusive scan over chunk counts; emit bucket totals
__global__ __launch_bounds__(512) void bkt_bscan(int* __restrict__ hist,
        int* __restrict__ btot) {
    __shared__ int sh[512];
    const int b = blockIdx.x, t = threadIdx.x;
    int v = hist[b * NBLK + t];
    sh[t] = v;
    __syncthreads();
    for (int d = 1; d < 512; d <<= 1) {
        int u = (t >= d) ? sh[t - d] : 0;
        __syncthreads();
        sh[t] += u;
        __syncthreads();
    }
    hist[b * NBLK + t] = sh[t] - v;        // exclusive
    if (t == 511) btot[b] = sh[511];
}

// scatter packed (local_dst<<18 | src); computes bucket bases from btot in LDS
__global__ __launch_bounds__(512) void bkt_scatter(const int* __restrict__ src,
        const int* __restrict__ dst, const int* __restrict__ hist,
        const int* __restrict__ btot, int* __restrict__ bucketed,
        int NBK, int CHUNK, int E) {
    __shared__ int sc[512];
    __shared__ int lc[512];
    const int blk = blockIdx.x, t = threadIdx.x;
    int v = (t < NBK) ? btot[t] : 0;
    sc[t] = v;
    __syncthreads();
    for (int d = 1; d < 512; d <<= 1) {
        int u = (t >= d) ? sc[t - d] : 0;
        __syncthreads();
        sc[t] += u;
        __syncthreads();
    }
    if (t < NBK) lc[t] = (sc[t] - v) + hist[t * NBLK + blk];
    __syncthreads();
    const int e0 = blk * CHUNK, e1 = min(E, e0 + CHUNK);
    const int nq = (e1 - e0) >> 2;
    const int4* d4 = (const int4*)(dst + e0);
    const int4* s4 = (const int4*)(src + e0);
    for (int q = t; q < nq; q += 512) {
        int4 d = d4[q];
        int4 s = s4[q];
        int sl;
        sl = atomicAdd(&lc[d.x >> BSHIFT], 1); bucketed[sl] = ((d.x & BMASK) << 18) | s.x;
        sl = atomicAdd(&lc[d.y >> BSHIFT], 1); bucketed[sl] = ((d.y & BMASK) << 18) | s.y;
        sl = atomicAdd(&lc[d.z >> BSHIFT], 1); bucketed[sl] = ((d.z & BMASK) << 18) | s.z;
        sl = atomicAdd(&lc[d.w >> BSHIFT], 1); bucketed[sl] = ((d.w & BMASK) << 18) | s.w;
    }
    for (int e = e0 + (nq << 2) + t; e < e1; e += 512) {
        int d = dst[e];
        int slot = atomicAdd(&lc[d >> BSHIFT], 1);
        bucketed[slot] = ((d & BMASK) << 18) | src[e];
    }
}

// per-bucket CSR finalize; computes own boff from btot in LDS
__global__ __launch_bounds__(512) void bkt_csr(const int* __restrict__ bucketed,
        const int* __restrict__ btot, int* __restrict__ off,
        int* __restrict__ elist, int NBK, int N, int E) {
    __shared__ int sc[512];
    __shared__ int lh[256];
    __shared__ int lc[256];
    __shared__ int sh[256];
    const int b = blockIdx.x, t = threadIdx.x;
    int v = (t < NBK) ? btot[t] : 0;
    sc[t] = v;
    __syncthreads();
    for (int d = 1; d < 512; d <<= 1) {
        int u = (t >= d) ? sc[t - d] : 0;
        __syncthreads();
        sc[t] += u;
        __syncthreads();
    }
    const int cnt  = btot[b];
    const int base = sc[b] - cnt;        // exclusive boff[b]
    if (b == 0 && t == 0) off[N] = E;
    const int b0 = b << BSHIFT;
    const int R = min(N - b0, 256);
    if (t < 256) lh[t] = 0;
    __syncthreads();
    for (int i = t; i < cnt; i += 512) atomicAdd(&lh[bucketed[base + i] >> 18], 1);
    __syncthreads();
    int v0 = 0;
    if (t < 256) { v0 = lh[t]; sh[t] = v0; }
    __syncthreads();
    for (int d = 1; d < 256; d <<= 1) {
        int u = 0;
        if (t < 256 && t >= d) u = sh[t - d];
        __syncthreads();
        if (t < 256) sh[t] += u;
        __syncthreads();
    }
    if (t < 256) { int ex = sh[t] - v0; lh[t] = ex; lc[t] = ex; }
    __syncthreads();
    if (t < R) off[b0 + t] = base + lh[t];
    for (int i = t; i < cnt; i += 512) {
        int p = bucketed[base + i];
        int rk = atomicAdd(&lc[p >> 18], 1);
        elist[base + rk] = p & 0x3FFFF;
    }
}

// ============ fused gather (+affine) -> LDS -> MFMA GEMM (+relu,+stats) =======
// A block gathers NPB consecutive node rows into LDS, then its 4 waves run the
// following F->FOUT GEMM on those SPB row-stripes. Stats go to 8 strided copies.
template<int F, int FOUT, bool STATS, bool AFFINE, typename OutT>
__global__ __launch_bounds__(256) void gather_gemm(const int* __restrict__ off,
        const int* __restrict__ elist, const f16* __restrict__ in,
        const f16* __restrict__ Wf, const float* __restrict__ bias,
        const float* __restrict__ av, const float* __restrict__ ab,
        OutT* __restrict__ Out, float* __restrict__ stats, int N) {
    constexpr int TPN = F / 8;         // lanes per node in gather
    constexpr int NPB = 256 / TPN;     // nodes per block
    constexpr int SPB = NPB / 16;      // 16-row stripes per block
    constexpr int WPS = 4 / SPB;       // waves per stripe
    constexpr int NTF = FOUT / 16;     // total n-tiles
    constexpr int NTW = NTF / WPS;     // n-tiles per wave
    constexpr int NS = F / 32;         // k-steps
    constexpr int LDW = F + 8;         // LDS row stride (f16), +16B pad
    __shared__ f16 Hl[NPB * LDW];
    __shared__ float Ss[STATS ? 2 * FOUT : 1];
    if (STATS) for (int z = threadIdx.x; z < 2 * FOUT; z += 256) Ss[z] = 0.0f;

    const int base = blockIdx.x * NPB;
    const int rl = threadIdx.x / TPN;
    const int i = base + rl;
    const int l = threadIdx.x & (TPN - 1);
    if (i < N) {
        const int j0 = l * 8;
        const f16x8* __restrict__ inv = (const f16x8*)in;
        f16x8 s = inv[(size_t)i * TPN + l];
        float a[8];
#pragma unroll
        for (int u = 0; u < 8; u++) a[u] = (float)s[u];
        int k = off[i], e = off[i + 1];
        const float cnt = (float)(e - k + 1);
        f16x8 c0, c1, c2, c3;
        if (k + 4 <= e) {
            c0 = inv[(size_t)elist[k + 0] * TPN + l];
            c1 = inv[(size_t)elist[k + 1] * TPN + l];
            c2 = inv[(size_t)elist[k + 2] * TPN + l];
            c3 = inv[(size_t)elist[k + 3] * TPN + l];
            k += 4;
            for (; k + 4 <= e; k += 4) {
                f16x8 d0 = inv[(size_t)elist[k + 0] * TPN + l];
                f16x8 d1 = inv[(size_t)elist[k + 1] * TPN + l];
                f16x8 d2 = inv[(size_t)elist[k + 2] * TPN + l];
                f16x8 d3 = inv[(size_t)elist[k + 3] * TPN + l];
#pragma unroll
                for (int u = 0; u < 8; u++)
                    a[u] += ((float)c0[u] + (float)c1[u]) + ((float)c2[u] + (float)c3[u]);
                c0 = d0; c1 = d1; c2 = d2; c3 = d3;
            }
#pragma unroll
            for (int u = 0; u < 8; u++)
                a[u] += ((float)c0[u] + (float)c1[u]) + ((float)c2[u] + (float)c3[u]);
        }
        for (; k < e; k++) {
            f16x8 p = inv[(size_t)elist[k] * TPN + l];
#pragma unroll
            for (int u = 0; u < 8; u++) a[u] += (float)p[u];
        }
        if (AFFINE) {
            float4 vv0 = *(const float4*)(av + j0);
            float4 vv1 = *(const float4*)(av + j0 + 4);
            float4 bb0 = *(const float4*)(ab + j0);
            float4 bb1 = *(const float4*)(ab + j0 + 4);
            a[0] = fmaxf(fmaf(cnt, vv0.x, a[0] + bb0.x), 0.0f);
            a[1] = fmaxf(fmaf(cnt, vv0.y, a[1] + bb0.y), 0.0f);
            a[2] = fmaxf(fmaf(cnt, vv0.z, a[2] + bb0.z), 0.0f);
            a[3] = fmaxf(fmaf(cnt, vv0.w, a[3] + bb0.w), 0.0f);
            a[4] = fmaxf(fmaf(cnt, vv1.x, a[4] + bb1.x), 0.0f);
            a[5] = fmaxf(fmaf(cnt, vv1.y, a[5] + bb1.y), 0.0f);
            a[6] = fmaxf(fmaf(cnt, vv1.z, a[6] + bb1.z), 0.0f);
            a[7] = fmaxf(fmaf(cnt, vv1.w, a[7] + bb1.w), 0.0f);
        }
        f16x8 o;
#pragma unroll
        for (int u = 0; u < 8; u++) o[u] = (f16)a[u];
        *(f16x8*)&Hl[rl * LDW + j0] = o;
    }
    __syncthreads();

    const int wid = threadIdx.x >> 6;
    const int lane = threadIdx.x & 63;
    const int col = lane & 15;
    const int quad = lane >> 4;
    const int sid = wid / WPS;
    const int cg = wid % WPS;
    const int m0 = base + sid * 16;
    if (m0 < N) {
        f16x8 Bf[NS][NTW];
#pragma unroll
        for (int s = 0; s < NS; s++)
#pragma unroll
            for (int t = 0; t < NTW; t++)
                Bf[s][t] = *(const f16x8*)&Wf[((s * NTF + cg * NTW + t) << 9) + (lane << 3)];
        f32x4 acc[NTW];
#pragma unroll
        for (int t = 0; t < NTW; t++) {
            float b = bias[(cg * NTW + t) * 16 + col];
            acc[t] = (f32x4){b, b, b, b};
        }
        f16x8 Af[NS];
        const int rbase = (sid * 16 + col) * LDW + quad * 8;
#pragma unroll
        for (int s = 0; s < NS; s++) Af[s] = *(const f16x8*)&Hl[rbase + s * 32];
#pragma unroll
        for (int t = 0; t < NTW; t++)
#pragma unroll
            for (int s = 0; s < NS; s++)
                acc[t] = __builtin_amdgcn_mfma_f32_16x16x32_f16(Af[s], Bf[s][t], acc[t], 0, 0, 0);
#pragma unroll
        for (int t = 0; t < NTW; t++) {
            float v0 = fmaxf(acc[t][0], 0.0f);
            float v1 = fmaxf(acc[t][1], 0.0f);
            float v2 = fmaxf(acc[t][2], 0.0f);
            float v3 = fmaxf(acc[t][3], 0.0f);
            OutT* o = Out + (size_t)(m0 + quad * 4) * FOUT + (cg * NTW + t) * 16 + col;
            o[0]        = (OutT)v0;
            o[FOUT]     = (OutT)v1;
            o[2 * FOUT] = (OutT)v2;
            o[3 * FOUT] = (OutT)v3;
            if (STATS) {
                float s1 = (v0 + v1) + (v2 + v3);
                float s2 = (v0 * v0 + v1 * v1) + (v2 * v2 + v3 * v3);
                s1 += __shfl_xor(s1, 16); s1 += __shfl_xor(s1, 32);
                s2 += __shfl_xor(s2, 16); s2 += __shfl_xor(s2, 32);
                if (quad == 0) {
                    atomicAdd(&Ss[(cg * NTW + t) * 16 + col], s1);
                    atomicAdd(&Ss[FOUT + (cg * NTW + t) * 16 + col], s2);
                }
            }
        }
    }
    if (STATS) {
        __syncthreads();
        float* stc = stats + (blockIdx.x & 7) * 2 * FOUT;
        for (int z = threadIdx.x; z < 2 * FOUT; z += 256) atomicAdd(&stc[z], Ss[z]);
    }
}

// ===== fused layer prep: block 0 computes v[]; blocks 1.. do scaled wfrag =====
__global__ __launch_bounds__(256) void layerprep_kernel(const float* __restrict__ W,
        f16* __restrict__ Wh, int FIN, int FOUT,
        const float* __restrict__ stats, int NC, const float* __restrict__ g,
        const float* __restrict__ be, float* __restrict__ v, float invN) {
    if (blockIdx.x == 0) {
        int j = threadIdx.x;
        if (j >= FOUT) return;
        float acc = 0.0f;
        for (int k = 0; k < FIN; k++) {
            float s1 = 0.0f, s2 = 0.0f;
            for (int c = 0; c < NC; c++) {
                s1 += stats[c * 2 * FIN + k];
                s2 += stats[c * 2 * FIN + FIN + k];
            }
            float mu = s1 * invN;
            float var = fmaxf(s2 * invN - mu * mu, 0.0f);
            float sc = rsqrtf(var + BN_EPS) * g[k];
            float sh = be[k] - mu * sc;
            acc = fmaf(sh, W[(size_t)k * FOUT + j], acc);
        }
        v[j] = acc;
        return;
    }
    int f = (blockIdx.x - 1) * 256 + threadIdx.x;
    if (f < FIN * FOUT) wfrag_one(W, Wh, FIN, FOUT, f, stats, NC, g, invN);
}

// ======= standalone MFMA GEMM (pre-fragged W, column-tiled) ===================
template<int FIN, int FOUT, int CT, bool STATS, bool RELU, bool BIAS, typename OutT>
__global__ __launch_bounds__(256) void gemm_mfma(const f16* __restrict__ A,
        const f16* __restrict__ Wf, const float* __restrict__ bias,
        OutT* __restrict__ Out, float* __restrict__ stats, int N) {
    constexpr int NS = FIN / 32;
    constexpr int NTF = FOUT / 16;
    constexpr int NT = CT / 16;
    constexpr int NCB = FOUT / CT;
    __shared__ float Ss[STATS ? 2 * CT : 1];
    if (STATS) {
        for (int i = threadIdx.x; i < 2 * CT; i += 256) Ss[i] = 0.0f;
        __syncthreads();
    }
    const int cb = blockIdx.x % NCB;
    const int rb = blockIdx.x / NCB;
    const int RB = gridDim.x / NCB;
    const int t0 = cb * NT;
    const int wid = threadIdx.x >> 6;
    const int lane = threadIdx.x & 63;
    const int col = lane & 15;
    const int quad = lane >> 4;

    f16x8 Bf[NS][NT];
#pragma unroll
    for (int s = 0; s < NS; s++)
#pragma unroll
        for (int t = 0; t < NT; t++)
            Bf[s][t] = *(const f16x8*)&Wf[((s * NTF + t0 + t) << 9) + (lane << 3)];

    float bj[NT];
#pragma unroll
    for (int t = 0; t < NT; t++) bj[t] = BIAS ? bias[(t0 + t) * 16 + col] : 0.0f;

    float ls[NT], ls2[NT];
#pragma unroll
    for (int t = 0; t < NT; t++) { ls[t] = 0.0f; ls2[t] = 0.0f; }

    const int S = N >> 4;
    for (int sidx = rb * 4 + wid; sidx < S; sidx += RB * 4) {
        const int m0 = sidx << 4;
        const f16* a0 = A + (size_t)(m0 + col) * FIN + (quad << 3);
        f16x8 Af[NS];
#pragma unroll
        for (int s = 0; s < NS; s++) Af[s] = *(const f16x8*)(a0 + s * 32);
        f32x4 acc[NT];
#pragma unroll
        for (int t = 0; t < NT; t++) acc[t] = (f32x4){bj[t], bj[t], bj[t], bj[t]};
#pragma unroll
        for (int t = 0; t < NT; t++)
#pragma unroll
            for (int s = 0; s < NS; s++)
                acc[t] = __builtin_amdgcn_mfma_f32_16x16x32_f16(Af[s], Bf[s][t], acc[t], 0, 0, 0);
#pragma unroll
        for (int t = 0; t < NT; t++) {
            float v0 = acc[t][0], v1 = acc[t][1], v2 = acc[t][2], v3 = acc[t][3];
            if (RELU) {
                v0 = fmaxf(v0, 0.0f); v1 = fmaxf(v1, 0.0f);
                v2 = fmaxf(v2, 0.0f); v3 = fmaxf(v3, 0.0f);
            }
            if (STATS) {
                ls[t]  += (v0 + v1) + (v2 + v3);
                ls2[t] += (v0 * v0 + v1 * v1) + (v2 * v2 + v3 * v3);
            }
            OutT* o = Out + (size_t)(m0 + quad * 4) * FOUT + (t0 + t) * 16 + col;
            o[0]        = (OutT)v0;
            o[FOUT]     = (OutT)v1;
            o[2 * FOUT] = (OutT)v2;
            o[3 * FOUT] = (OutT)v3;
        }
    }

    if (STATS) {
#pragma unroll
        for (int t = 0; t < NT; t++) {
            float s1 = ls[t], s2 = ls2[t];
            s1 += __shfl_xor(s1, 16); s1 += __shfl_xor(s1, 32);
            s2 += __shfl_xor(s2, 16); s2 += __shfl_xor(s2, 32);
            if (quad == 0) {
                atomicAdd(&Ss[t * 16 + col], s1);
                atomicAdd(&Ss[CT + t * 16 + col], s2);
            }
        }
        __syncthreads();
        for (int i = threadIdx.x; i < CT; i += 256) {
            atomicAdd(&stats[cb * CT + i], Ss[i]);
            atomicAdd(&stats[FOUT + cb * CT + i], Ss[CT + i]);
        }
    }
}

// ========= layer-3 BN + segmented pool (batch sorted; stats = NC copies) ======
__global__ __launch_bounds__(256) void bn_pool_kernel(const float* __restrict__ y,
        const float* __restrict__ stats, int NC, const float* __restrict__ gw,
        const float* __restrict__ bw, const int* __restrict__ batch,
        float* __restrict__ pool, int N, float invN) {
    constexpr int F = 32, CH = 64;
    int q = threadIdx.x >> 5;
    int j = threadIdx.x & 31;
    int r0 = (blockIdx.x * 8 + q) * CH;
    if (r0 >= N) return;
    int r1 = min(r0 + CH, N);
    float s1 = 0.0f, s2 = 0.0f;
    for (int c = 0; c < NC; c++) {
        s1 += stats[c * 2 * F + j];
        s2 += stats[c * 2 * F + F + j];
    }
    float mu = s1 * invN;
    float var = fmaxf(s2 * invN - mu * mu, 0.0f);
    float sc = rsqrtf(var + BN_EPS) * gw[j];
    float sh = bw[j] - mu * sc;
    int curg = batch[r0];
    float acc = 0.0f;
    for (int r = r0; r < r1; r++) {
        int g = batch[r];
        if (g != curg) {
            atomicAdd(pool + (size_t)curg * 32 + j, acc);
            acc = 0.0f;
            curg = g;
        }
        acc = fmaf(y[(size_t)r * 32 + j], sc, sh + acc);
    }
    atomicAdd(pool + (size_t)curg * 32 + j, acc);
}

// ================= FC head =================
__global__ __launch_bounds__(128) void fc_kernel(const float* __restrict__ pool,
        const float* __restrict__ Wf1, const float* __restrict__ bf1,
        const float* __restrict__ Wf2, const float* __restrict__ bf2,
        const float* __restrict__ Wf3, const float* __restrict__ bf3,
        float* __restrict__ out) {
    __shared__ float zin[32];
    __shared__ float h1[128];
    __shared__ float h2[64];
    const int gidx = blockIdx.x;
    const int t = threadIdx.x;
    if (t < 32) zin[t] = pool[(size_t)gidx * 32 + t];
    __syncthreads();
    {
        float a = bf1[t];
        for (int k = 0; k < 32; k++) a = fmaf(zin[k], Wf1[k * 128 + t], a);
        h1[t] = fmaxf(a, 0.0f);
    }
    __syncthreads();
    if (t < 64) {
        float a = bf2[t];
        for (int k = 0; k < 128; k++) a = fmaf(h1[k], Wf2[k * 64 + t], a);
        h2[t] = fmaxf(a, 0.0f);
    }
    __syncthreads();
    if (t < 10) {
        float a = bf3[t];
        for (int k = 0; k < 64; k++) a = fmaf(h2[k], Wf3[k * 10 + t], a);
        out[(size_t)gidx * 10 + t] = a;
    }
}

extern "C" void kernel_launch(void* const* d_in, const int* in_sizes, int n_in,
                              void* d_out, int out_size, void* d_ws, size_t ws_size,
                              hipStream_t stream) {
    const float* x   = (const float*)d_in[0];
    const int*  ei   = (const int*)d_in[1];
    const int*  batch= (const int*)d_in[2];
    const float* W1a = (const float*)d_in[3];  const float* b1a = (const float*)d_in[4];
    const float* W1b = (const float*)d_in[5];  const float* b1b = (const float*)d_in[6];
    const float* g1  = (const float*)d_in[7];  const float* be1 = (const float*)d_in[8];
    const float* W2a = (const float*)d_in[9];  const float* b2a = (const float*)d_in[10];
    const float* W2b = (const float*)d_in[11]; const float* b2b = (const float*)d_in[12];
    const float* g2  = (const float*)d_in[13]; const float* be2 = (const float*)d_in[14];
    const float* W3a = (const float*)d_in[15]; const float* b3a = (const float*)d_in[16];
    const float* W3b = (const float*)d_in[17]; const float* b3b = (const float*)d_in[18];
    const float* g3  = (const float*)d_in[19]; const float* be3 = (const float*)d_in[20];
    const float* Wf1 = (const float*)d_in[21]; const float* bf1 = (const float*)d_in[22];
    const float* Wf2 = (const float*)d_in[23]; const float* bf2 = (const float*)d_in[24];
    const float* Wf3 = (const float*)d_in[25]; const float* bf3 = (const float*)d_in[26];

    const int N = in_sizes[2];
    const int E = in_sizes[1] / 2;
    const int G = out_size / 10;
    const int* src = ei;
    const int* dst = ei + E;

    const int NBK = (N + BMASK) >> BSHIFT;           // 391 for N=100K
    const int CHUNK = (((E + NBLK - 1) / NBLK) + 3) & ~3;  // 4-aligned

    // ---- ws layout ----
    float* B0   = (float*)d_ws;              // N*128 f32 worth (= N*256 f16)
    float* B1   = B0 + (size_t)N * 128;
    float* pool = B1 + (size_t)N * 128;      // G*32
    float* st1  = pool + (size_t)G * 32;     // 256 (single copy)
    float* st2c = st1 + 256;                 // 8 * 128
    float* st3c = st2c + 1024;               // 8 * 64
    int* off    = (int*)(st3c + 512);        // N+1
    int* elist  = off + (N + 1);             // E
    float* v2   = (float*)(elist + E);       // 64
    float* v3   = v2 + 64;                   // 32
    int* btot   = (int*)(v3 + 32);           // NBK
    f16* Wh1a   = (f16*)(btot + NBK);        // 8K
    f16* Wh1b   = Wh1a + 64 * 128;           // 16K
    f16* Wh2a   = Wh1b + 128 * 128;          // 8K
    f16* Wh2b   = Wh2a + 128 * 64;           // 4K
    f16* Wh3a   = Wh2b + 64 * 64;            // 2K
    f16* Wh3b   = Wh3a + 64 * 32;            // 1K

    // ---- CSR-phase aliases in B1 (dead before B1's activation use) ----
    int* bucketed = (int*)B1;                // E ints (12.8 MB)
    int* hist     = bucketed + E;            // NBK*NBLK ints (800 KB)

    // ---- activation aliases (stream-order safe) ----
    f16* xh    = (f16*)B0;                    // N*64  [B0 slot A]
    f16* H1    = (f16*)B0 + (size_t)N * 64;   // N*128 [B0 slot B]
    f16* Y1    = (f16*)B1 + (size_t)N * 64;   // N*128 [B1 slot B] (hist dead)
    f16* Z1    = (f16*)B0;                    // N*64  [B0 slot A] (xh dead)
    f16* Y2    = (f16*)B0 + (size_t)N * 64;   // N*64  [B0 slot B] (H1 dead)
    f16* Z2    = (f16*)B0;                    // N*32  [B0 slot A] (Z1 dead)
    float* Y3  = B1 + (size_t)N * 64;         // N*32 f32 [B1 slot B] (Y1 dead)

    hipMemsetAsync(pool, 0, ((size_t)G * 32 + 256 + 1024 + 512) * sizeof(float), stream);

    const float invN = 1.0f / (float)N;
    const int GG = 640;

    // ---- fused setup: conv + static W frags + bucket count ----
    {
        int BC = (N * 16 + 255) / 256;
        setup_count<<<BC + 116 + NBLK, 256, 0, stream>>>(
            (const float4*)x, (f16x4*)xh, N * 16,
            W1a, Wh1a, W1b, Wh1b, W2b, Wh2b, W3b, Wh3b,
            dst, hist, NBK, CHUNK, E);
    }

    // ---- CSR build ----
    bkt_bscan  <<<NBK, 512, 0, stream>>>(hist, btot);
    bkt_scatter<<<NBLK, 512, 0, stream>>>(src, dst, hist, btot, bucketed, NBK, CHUNK, E);
    bkt_csr    <<<NBK, 512, 0, stream>>>(bucketed, btot, off, elist, NBK, N, E);

    // ---- Layer 1: [gather1 + gemm1a] fused -> gemm1b(stats st1) ----
    gather_gemm<64, 128, false, false, f16><<<(N + 31) / 32, 256, 0, stream>>>(
        off, elist, xh, Wh1a, b1a, nullptr, nullptr, H1, nullptr, N);
    gemm_mfma<128, 128, 64, true, true, true, f16><<<GG, 256, 0, stream>>>(H1, Wh1b, b1b, Y1, st1, N);

    // ---- Layer 2 (commuted): prep -> gemm2a -> [gather2 + gemm2b(stats st2c)] ----
    layerprep_kernel<<<33, 256, 0, stream>>>(W2a, Wh2a, 128, 64, st1, 1, g1, be1, v2, invN);
    gemm_mfma<128, 64, 64, false, false, false, f16><<<GG, 256, 0, stream>>>(Y1, Wh2a, nullptr, Z1, nullptr, N);
    gather_gemm<64, 64, true, true, f16><<<(N + 31) / 32, 256, 0, stream>>>(
        off, elist, Z1, Wh2b, b2b, v2, b2a, Y2, st2c, N);

    // ---- Layer 3 (commuted): prep -> gemm3a -> [gather3 + gemm3b(stats st3c)] ----
    layerprep_kernel<<<9, 256, 0, stream>>>(W3a, Wh3a, 64, 32, st2c, 8, g2, be2, v3, invN);
    gemm_mfma<64, 32, 32, false, false, false, f16><<<GG, 256, 0, stream>>>(Y2, Wh3a, nullptr, Z2, nullptr, N);
    gather_gemm<32, 32, true, true, float><<<(N + 63) / 64, 256, 0, stream>>>(
        off, elist, Z2, Wh3b, b3b, v3, b3a, Y3, st3c, N);

    // ---- BN3 + segmented pool ----
    bn_pool_kernel<<<(N + 511) / 512, 256, 0, stream>>>(Y3, st3c, 8, g3, be3, batch, pool, N, invN);

    // ---- pooled MLP head ----
    fc_kernel<<<G, 128, 0, stream>>>(pool, Wf1, bf1, Wf2, bf2, Wf3, bf3, (float*)d_out);
}